// Round 2
// baseline (223.797 us; speedup 1.0000x reference)
//
#include <hip/hip_runtime.h>
#include <hip/hip_bf16.h>
#include <stdint.h>

#define N_   64
#define L_   1024
#define D_   512
#define S_   127
#define OUT_ 300
#define NT_  20            // 20 col-tiles of 16 -> 320 padded cols
#define OUTP (NT_*16)      // 320
#define EPS_ 1e-5f
#define M_TOTAL (N_*S_)    // 8128

// prep kernel block ranges
#define WBLK 640           // OUTP*D_/256  : w_lin f32 -> bf16 (padded 320 rows)
#define UBLK 32            // N_*D_/4/256  : use = t1[:,0,:]
#define MBLK (M_TOTAL/2)   // 4064         : span means, 2 spans/block

// gemm kernel
#define BM   32
#define GBLK (M_TOTAL/BM)  // 254 (exact)
#define ASTR 520           // LDS A row stride in bf16 (1040 B: +16B depads banks)
#define HSTR 320           // epilogue h stride (floats)

typedef __attribute__((ext_vector_type(4))) float  float4v;
typedef __attribute__((ext_vector_type(8))) __bf16 bf16x8;
typedef __attribute__((ext_vector_type(4))) __bf16 bf16x4;

// ---------------------------------------------------------------------------
// prep: one launch doing (a) weight bf16 conversion, (b) use-copy,
// (c) span means -> bf16 A[8128][512]. Huge grid, tiny resources ->
// max occupancy; span reads are CONTIGUOUS 16 KiB chunks (8 rows x 2 KiB).
// ---------------------------------------------------------------------------
__global__ __launch_bounds__(256) void prep(
    const float* __restrict__ t1, const int* __restrict__ wseq,
    const float* __restrict__ w_lin,
    __bf16* __restrict__ wbf, __bf16* __restrict__ A,
    float* __restrict__ use_out)
{
    const int blk = blockIdx.x;
    const int tid = threadIdx.x;

    if (blk < WBLK) {                       // --- w_lin -> bf16, pad rows>=300
        int idx = blk * 256 + tid;          // 320*512 threads
        int o = idx >> 9, d = idx & (D_ - 1);
        float v = (o < OUT_) ? w_lin[o * D_ + d] : 0.0f;
        wbf[idx] = (__bf16)v;
    } else if (blk < WBLK + UBLK) {         // --- use = t1[:,0,:]
        int idx = (blk - WBLK) * 256 + tid; // 8192 threads, float4 each
        int n = idx >> 7, dg = idx & 127;
        float4v v = *(const float4v*)(t1 + (size_t)n * L_ * D_ + dg * 4);
        *(float4v*)(use_out + n * D_ + dg * 4) = v;
    } else {                                // --- span means, 2 spans per block
        int sp = (blk - WBLK - UBLK) * 2 + (tid >> 7);   // global span < 8128
        int cg = tid & 127;                              // float4 col group
        int nn = sp / S_;
        int st = min(wseq[sp * 2 + 0], L_ - 3);          // min(start, li-1)
        int en = min(wseq[sp * 2 + 1], L_ - 2);          // min(end, li)
        int cnt = en - st;
        const float* base = t1 + ((size_t)nn * L_ + 1 + st) * D_ + cg * 4;
        float4v s4 = {0.f, 0.f, 0.f, 0.f};
        if (cnt == 8) {                     // fast path (always true here)
            #pragma unroll
            for (int j = 0; j < 8; ++j) s4 += *(const float4v*)(base + j * D_);
        } else {
            for (int j = 0; j < cnt; ++j)   s4 += *(const float4v*)(base + j * D_);
        }
        float ic = 1.0f / (float)cnt;
        s4 *= ic;
        bf16x4 a4;
        a4[0] = (__bf16)s4[0]; a4[1] = (__bf16)s4[1];
        a4[2] = (__bf16)s4[2]; a4[3] = (__bf16)s4[3];
        *(bf16x4*)(A + (size_t)sp * D_ + cg * 4) = a4;
    }
}

// ---------------------------------------------------------------------------
// gemm_ln: [8128 x 512]bf16 @ [512 x 320]bf16 -> bias -> LayerNorm(300).
// BM=32, 512 threads (8 waves: 2 row-tiles x 4 col-groups of 5 tiles).
// A-tile staged to LDS once; K-loop is BARRIER-FREE: B fragments read
// directly from global (320 KiB weights are L2-resident on every XCD).
// ---------------------------------------------------------------------------
__global__ __launch_bounds__(512) void gemm_ln(
    const __bf16* __restrict__ A, const __bf16* __restrict__ wbf,
    const float* __restrict__ b_lin, const float* __restrict__ gamma,
    const float* __restrict__ beta, float* __restrict__ out)
{
    __shared__ __align__(16) char smem[BM * HSTR * 4];   // 40960 B (A: 33280 aliased)
    __bf16* Alds = (__bf16*)smem;      // [32][520]
    float*  hlds = (float*)smem;       // [32][320], aliased after K-loop barrier

    const int tid  = threadIdx.x;
    const int m0   = blockIdx.x * BM;
    const int lane = tid & 63;
    const int wave = tid >> 6;         // 0..7
    const int quad = lane >> 4;
    const int ln16 = lane & 15;
    const int rt   = wave >> 2;        // row tile 0..1
    const int cg   = wave & 3;         // col group -> tiles [cg*5, cg*5+5)

    // stage A: 32 x 512 bf16 = 2048 x 16B groups, coalesced
    #pragma unroll
    for (int it = 0; it < 4; ++it) {
        int idx = tid + it * 512;      // < 2048
        int row = idx >> 6, kg = idx & 63;
        bf16x8 v = *(const bf16x8*)(A + (size_t)(m0 + row) * D_ + kg * 8);
        *(bf16x8*)(Alds + row * ASTR + kg * 8) = v;
    }
    __syncthreads();

    float4v acc[5];
    #pragma unroll
    for (int i = 0; i < 5; ++i) acc[i] = float4v{0.f, 0.f, 0.f, 0.f};

    const __bf16* bbase  = wbf + (size_t)(cg * 80 + ln16) * D_ + quad * 8;
    const __bf16* albase = Alds + (rt * 16 + ln16) * ASTR + quad * 8;

    // fully unrolled, no barriers: compiler pipelines B global loads over MFMAs
    #pragma unroll
    for (int kt = 0; kt < 8; ++kt) {
        #pragma unroll
        for (int ks = 0; ks < 2; ++ks) {
            const int kk = kt * 64 + ks * 32;
            bf16x8 af = *(const bf16x8*)(albase + kk);
            #pragma unroll
            for (int i = 0; i < 5; ++i) {
                bf16x8 bfr = *(const bf16x8*)(bbase + (size_t)i * 16 * D_ + kk);
                acc[i] = __builtin_amdgcn_mfma_f32_16x16x32_bf16(af, bfr, acc[i], 0, 0, 0);
            }
        }
    }
    __syncthreads();   // all A reads done before h aliases the LDS

    // epilogue: h = acc + bias (C layout: row = quad*4+reg, col = ln16)
    #pragma unroll
    for (int i = 0; i < 5; ++i) {
        const int col = (cg * 5 + i) * 16 + ln16;
        const float bl = (col < OUT_) ? b_lin[col] : 0.0f;
        #pragma unroll
        for (int r = 0; r < 4; ++r)
            hlds[(rt * 16 + quad * 4 + r) * HSTR + col] = acc[i][r] + bl;
    }
    __syncthreads();

    // LayerNorm over 300 cols; 16 threads/row, shfl-reduce in 16-lane groups
    const int r  = tid >> 4;           // 0..31
    const int c0 = tid & 15;
    float sum = 0.f, sq = 0.f;
    #pragma unroll
    for (int i = 0; i < 19; ++i) {
        int c = c0 + 16 * i;
        if (c < OUT_) { float v = hlds[r * HSTR + c]; sum += v; sq += v * v; }
    }
    #pragma unroll
    for (int off = 8; off > 0; off >>= 1) {
        sum += __shfl_xor(sum, off);
        sq  += __shfl_xor(sq,  off);
    }
    const float mu  = sum * (1.0f / OUT_);
    const float var = sq * (1.0f / OUT_) - mu * mu;
    const float rs  = rsqrtf(var + EPS_);
    float* orow = out + (size_t)(m0 + r) * OUT_;
    #pragma unroll
    for (int i = 0; i < 19; ++i) {
        int c = c0 + 16 * i;
        if (c < OUT_) {
            float v = hlds[r * HSTR + c];
            orow[c] = (v - mu) * rs * gamma[c] + beta[c];
        }
    }
}

extern "C" void kernel_launch(void* const* d_in, const int* in_sizes, int n_in,
                              void* d_out, int out_size, void* d_ws, size_t ws_size,
                              hipStream_t stream) {
    const float* t1    = (const float*)d_in[0];
    const int*   wseq  = (const int*)d_in[1];   // word_seq (int32); d_in[2] mask unused
    const float* w_lin = (const float*)d_in[3];
    const float* b_lin = (const float*)d_in[4];
    const float* gamma = (const float*)d_in[5];
    const float* beta  = (const float*)d_in[6];
    float* out  = (float*)d_out;

    // workspace: wbf 320*512*2 = 327680 B, then A 8128*512*2 = 8323072 B
    __bf16* wbf = (__bf16*)d_ws;
    __bf16* A   = (__bf16*)((char*)d_ws + (size_t)OUTP * D_ * 2);

    prep<<<WBLK + UBLK + MBLK, 256, 0, stream>>>(
        t1, wseq, w_lin, wbf, A, out + (size_t)M_TOTAL * OUT_);
    gemm_ln<<<GBLK, 512, 0, stream>>>(A, wbf, b_lin, gamma, beta, out);
}